// Round 9
// baseline (2825.334 us; speedup 1.0000x reference)
//
#include <hip/hip_runtime.h>

#define WF 64

__device__ inline float wredsum(float v) {
#pragma unroll
  for (int m = 32; m; m >>= 1) v += __shfl_xor(v, m, WF);
  return v;
}
__device__ inline float4 wredsum4(float4 v) {
#pragma unroll
  for (int m = 32; m; m >>= 1) {
    v.x += __shfl_xor(v.x, m, WF);
    v.y += __shfl_xor(v.y, m, WF);
    v.z += __shfl_xor(v.z, m, WF);
    v.w += __shfl_xor(v.w, m, WF);
  }
  return v;
}
__device__ inline float wredmin(float v) {
#pragma unroll
  for (int m = 32; m; m >>= 1) v = fminf(v, __shfl_xor(v, m, WF));
  return v;
}
__device__ inline float wredmax(float v) {
#pragma unroll
  for (int m = 32; m; m >>= 1) v = fmaxf(v, __shfl_xor(v, m, WF));
  return v;
}

__device__ inline float fastrcp(float x) {
  float r;
  asm("v_rcp_f32 %0, %1" : "=v"(r) : "v"(x));
  return r;
}

__device__ inline void atomAddF(float* p, float v) { unsafeAtomicAdd(p, v); }

__device__ inline unsigned short f2bf(float f) {
  unsigned u = __float_as_uint(f);
  unsigned r = u + 0x7FFFu + ((u >> 16) & 1u);
  return (unsigned short)(r >> 16);
}
__device__ inline float bf2f(unsigned short h) {
  return __uint_as_float(((unsigned)h) << 16);
}

// ---------------- shared-memory union ----------------
struct ConvS {
  float Wl[4096];
  float red[4][5];
};
struct GramS {
  float rowbuf[4][64];
  float colred[4][64];
  float mvs[4];
  int mis[4];
};
struct RankS {
  float A[64][65];
  float vbuf[64], wbuf[64], esh[64];
  float wpart[4][64];
  float2 de[64];
  float u[64], m0[64];
  float shn;
};
union SmemU {
  ConvS c;
  GramS g;
  RankS r;
};

// ---------------- init ----------------
__global__ __launch_bounds__(256) void k_init(int* degs, int* degd, float* G,
                                              float* colsum, float* scal, int n) {
  int i = blockIdx.x * 256 + threadIdx.x;
  if (i < n) { degs[i] = 1; degd[i] = 1; }
  if (i < 3 * 4096) G[i] = 0.f;
  if (i < 3 * 64) colsum[i] = 0.f;
  if (i < 64) scal[i] = 0.f;
}

// ---------------- degree histograms ----------------
__global__ __launch_bounds__(256) void k_deg(const int* src, const int* dst,
                                             int* degs, int* degd, int e) {
  int i = blockIdx.x * 256 + threadIdx.x;
  int stride = gridDim.x * 256;
  for (; i < e; i += stride) {
    atomicAdd(&degs[src[i]], 1);
    atomicAdd(&degd[dst[i]], 1);
  }
}

// ---------------- scan ----------------
__global__ __launch_bounds__(256) void k_scan1(const int* degd, int* start, int* bsum, int n) {
  __shared__ int sb[256];
  int t = threadIdx.x, i = blockIdx.x * 256 + t;
  int v = (i < n) ? degd[i] : 0;
  sb[t] = v;
  __syncthreads();
  for (int off = 1; off < 256; off <<= 1) {
    int add = (t >= off) ? sb[t - off] : 0;
    __syncthreads();
    sb[t] += add;
    __syncthreads();
  }
  if (i < n) start[i] = sb[t] - v;
  if (t == 255) bsum[blockIdx.x] = sb[255];
}

__global__ __launch_bounds__(512) void k_scan2(int* bsum, int nb) {
  __shared__ int sb[512];
  int t = threadIdx.x;
  int v = (t < nb) ? bsum[t] : 0;
  sb[t] = v;
  __syncthreads();
  for (int off = 1; off < 512; off <<= 1) {
    int add = (t >= off) ? sb[t - off] : 0;
    __syncthreads();
    sb[t] += add;
    __syncthreads();
  }
  if (t < nb) bsum[t] = sb[t] - v;
}

// scan3 + per-node constants: cn4 = {dis, 1/degs, degs^-0.5, degs^-1.5}
__global__ __launch_bounds__(256) void k_scan3(int* start, const int* bsum, int* cursor,
                                               const int* degs, const int* degd,
                                               float4* cn4, float* degsum, int n, int total) {
  int i = blockIdx.x * 256 + threadIdx.x;
  if (i < n) {
    int v = start[i] + bsum[i >> 8];
    start[i] = v;
    cursor[i] = v;
    float fs = (float)degs[i], fd = (float)degd[i];
    float rs_ = rsqrtf(fs);
    cn4[i] = make_float4(rsqrtf(fd), 1.f / fs, rs_, rs_ * rs_ * rs_);
    degsum[i] = fs + fd;
  }
  if (i == 0) start[n] = total;
}

// ---------------- counting-sort edges by dst ----------------
__global__ __launch_bounds__(256) void k_scatter(const int* src, const int* dst, int* cursor,
                                                 int* csr, int e, int n) {
  int i = blockIdx.x * 256 + threadIdx.x;
  int tot = e + n;
  if (i >= tot) return;
  int s, d;
  if (i < e) { s = src[i]; d = dst[i]; } else { s = i - e; d = i - e; }
  int pos = atomicAdd(&cursor[d], 1);
  csr[pos] = s;
}

// ---------------- encoder: Xb = bf16(x @ enc_w + b) ; nsq, P0 ----------------
__global__ __launch_bounds__(256) void k_enc(const float* __restrict__ x,
                                             const float* __restrict__ W,
                                             const float* __restrict__ b,
                                             const float4* __restrict__ cn4,
                                             unsigned short* __restrict__ Xb,
                                             float* __restrict__ nsq,
                                             float4* __restrict__ P, int n) {
  __shared__ float Wl[128 * 64];
  for (int idx = threadIdx.x; idx < 128 * 64; idx += 256) Wl[idx] = W[idx];
  __syncthreads();
  int w = threadIdx.x >> 6, c = threadIdx.x & 63;
  float bc = b[c];
  for (int node = blockIdx.x * 4 + w; node < n; node += gridDim.x * 4) {
    const float4* xr4 = (const float4*)(x + (size_t)node * 128);
    float acc = bc;
#pragma unroll
    for (int k4 = 0; k4 < 32; k4++) {
      float4 xv = xr4[k4];
      acc += xv.x * Wl[(k4 * 4 + 0) * 64 + c];
      acc += xv.y * Wl[(k4 * 4 + 1) * 64 + c];
      acc += xv.z * Wl[(k4 * 4 + 2) * 64 + c];
      acc += xv.w * Wl[(k4 * 4 + 3) * 64 + c];
    }
    Xb[(size_t)node * 64 + c] = f2bf(acc);
    float r = wredsum(acc * acc);
    if (c == 0) {
      nsq[node] = r;
      float4 c4 = cn4[node];
      P[node] = make_float4(c4.x, c4.y, c4.z, r * c4.w);
    }
  }
}

// ---------------- 4-deep unrolled bf16 gather core (per 16-lane group) -------------
template <int AGGC>
__device__ inline void gather4B(const unsigned short* __restrict__ Hb,
                                const float4* __restrict__ P,
                                const int* __restrict__ csr, int k0, int k1, int g, int l16,
                                float4& agg0, float4& agg1, float4& aggC,
                                float& su, float& sv) {
  int kk = k0 + g;
  int last = k1 - 1;
  int s0 = csr[min(kk, last)];
  int s1 = csr[min(kk + 4, last)];
  int s2 = csr[min(kk + 8, last)];
  int s3 = csr[min(kk + 12, last)];
  while (kk < k1) {
    int kn = kk + 16;
    ushort4 b0 = *(const ushort4*)(Hb + (size_t)s0 * 64 + 4 * l16);
    ushort4 b1 = *(const ushort4*)(Hb + (size_t)s1 * 64 + 4 * l16);
    ushort4 b2 = *(const ushort4*)(Hb + (size_t)s2 * 64 + 4 * l16);
    ushort4 b3 = *(const ushort4*)(Hb + (size_t)s3 * 64 + 4 * l16);
    float4 Q0 = P[s0], Q1 = P[s1], Q2 = P[s2], Q3 = P[s3];
    s0 = csr[min(kn, last)];
    s1 = csr[min(kn + 4, last)];
    s2 = csr[min(kn + 8, last)];
    s3 = csr[min(kn + 12, last)];
    float m1 = (kk + 4 < k1) ? 1.f : 0.f;
    float m2 = (kk + 8 < k1) ? 1.f : 0.f;
    float m3 = (kk + 12 < k1) ? 1.f : 0.f;
    {
      float hx = bf2f(b0.x), hy = bf2f(b0.y), hz = bf2f(b0.z), hw = bf2f(b0.w);
      agg0.x += hx; agg0.y += hy; agg0.z += hz; agg0.w += hw;
      agg1.x = fmaf(hx, Q0.y, agg1.x); agg1.y = fmaf(hy, Q0.y, agg1.y);
      agg1.z = fmaf(hz, Q0.y, agg1.z); agg1.w = fmaf(hw, Q0.y, agg1.w);
      if (AGGC) {
        aggC.x = fmaf(hx, Q0.x, aggC.x); aggC.y = fmaf(hy, Q0.x, aggC.y);
        aggC.z = fmaf(hz, Q0.x, aggC.z); aggC.w = fmaf(hw, Q0.x, aggC.w);
      }
      su += Q0.w; sv += Q0.z;
    }
    {
      float hx = bf2f(b1.x), hy = bf2f(b1.y), hz = bf2f(b1.z), hw = bf2f(b1.w);
      float y = Q1.y * m1;
      agg0.x = fmaf(hx, m1, agg0.x); agg0.y = fmaf(hy, m1, agg0.y);
      agg0.z = fmaf(hz, m1, agg0.z); agg0.w = fmaf(hw, m1, agg0.w);
      agg1.x = fmaf(hx, y, agg1.x); agg1.y = fmaf(hy, y, agg1.y);
      agg1.z = fmaf(hz, y, agg1.z); agg1.w = fmaf(hw, y, agg1.w);
      if (AGGC) {
        float xq = Q1.x * m1;
        aggC.x = fmaf(hx, xq, aggC.x); aggC.y = fmaf(hy, xq, aggC.y);
        aggC.z = fmaf(hz, xq, aggC.z); aggC.w = fmaf(hw, xq, aggC.w);
      }
      su = fmaf(Q1.w, m1, su); sv = fmaf(Q1.z, m1, sv);
    }
    {
      float hx = bf2f(b2.x), hy = bf2f(b2.y), hz = bf2f(b2.z), hw = bf2f(b2.w);
      float y = Q2.y * m2;
      agg0.x = fmaf(hx, m2, agg0.x); agg0.y = fmaf(hy, m2, agg0.y);
      agg0.z = fmaf(hz, m2, agg0.z); agg0.w = fmaf(hw, m2, agg0.w);
      agg1.x = fmaf(hx, y, agg1.x); agg1.y = fmaf(hy, y, agg1.y);
      agg1.z = fmaf(hz, y, agg1.z); agg1.w = fmaf(hw, y, agg1.w);
      if (AGGC) {
        float xq = Q2.x * m2;
        aggC.x = fmaf(hx, xq, aggC.x); aggC.y = fmaf(hy, xq, aggC.y);
        aggC.z = fmaf(hz, xq, aggC.z); aggC.w = fmaf(hw, xq, aggC.w);
      }
      su = fmaf(Q2.w, m2, su); sv = fmaf(Q2.z, m2, sv);
    }
    {
      float hx = bf2f(b3.x), hy = bf2f(b3.y), hz = bf2f(b3.z), hw = bf2f(b3.w);
      float y = Q3.y * m3;
      agg0.x = fmaf(hx, m3, agg0.x); agg0.y = fmaf(hy, m3, agg0.y);
      agg0.z = fmaf(hz, m3, agg0.z); agg0.w = fmaf(hw, m3, agg0.w);
      agg1.x = fmaf(hx, y, agg1.x); agg1.y = fmaf(hy, y, agg1.y);
      agg1.z = fmaf(hz, y, agg1.z); agg1.w = fmaf(hw, y, agg1.w);
      if (AGGC) {
        float xq = Q3.x * m3;
        aggC.x = fmaf(hx, xq, aggC.x); aggC.y = fmaf(hy, xq, aggC.y);
        aggC.z = fmaf(hz, xq, aggC.z); aggC.w = fmaf(hw, xq, aggC.w);
      }
      su = fmaf(Q3.w, m3, su); sv = fmaf(Q3.z, m3, sv);
    }
    kk = kn;
  }
}

// ---------------- streaming Gram/colsum/argmax of a bf16 matrix (rider) ----------------
__device__ void gram_block(GramS& S, const unsigned short* __restrict__ Hb, int n,
                           int gid, int NG, float* __restrict__ G,
                           float* __restrict__ colsum, float* __restrict__ bmv,
                           int* __restrict__ bmi, int t) {
  int w = t >> 6, lane = t & 63;
  int chunk = (n + NG - 1) / NG;
  int r0 = gid * chunk;
  int r1 = min(n, r0 + chunk);
  float Greg[16];
#pragma unroll
  for (int k = 0; k < 16; k++) Greg[k] = 0.f;
  float cacc = 0.f, best = -1.f;
  int bi = 0;
  int iters = (r1 - r0 + 3) >> 2;
  for (int it = 0; it < iters; it++) {
    int row = r0 + it * 4 + w;
    bool valid = row < r1;
    float v = valid ? bf2f(Hb[(size_t)row * 64 + lane]) : 0.f;
    float a = fabsf(v);
    cacc += a;
    float rsum = wredsum(a);
    if (valid && rsum > best) { best = rsum; bi = row; }
    S.rowbuf[w][lane] = v;
    __syncthreads();
#pragma unroll
    for (int rr = 0; rr < 4; rr++) {
      float hj = S.rowbuf[rr][lane];
#pragma unroll
      for (int k = 0; k < 16; k++) Greg[k] = fmaf(S.rowbuf[rr][w + 4 * k], hj, Greg[k]);
    }
    __syncthreads();
  }
#pragma unroll
  for (int k = 0; k < 16; k++) atomAddF(&G[(w + 4 * k) * 64 + lane], Greg[k]);
  S.colred[w][lane] = cacc;
  if (lane == 0) { S.mvs[w] = best; S.mis[w] = bi; }
  __syncthreads();
  if (t < 64) {
    float cs = S.colred[0][t] + S.colred[1][t] + S.colred[2][t] + S.colred[3][t];
    atomAddF(&colsum[t], cs);
  }
  if (t == 0) {
    float bv = S.mvs[0]; int bix = S.mis[0];
    for (int q = 1; q < 4; q++)
      if (S.mvs[q] > bv || (S.mvs[q] == bv && S.mis[q] < bix)) { bv = S.mvs[q]; bix = S.mis[q]; }
    bmv[gid] = bv;
    bmi[gid] = bix;
  }
}

// ---------------- Householder tridiag (trailing-only) + Sturm bisection --------------
__device__ float tridiag_sumsqrt(RankS& S, int t) {
  bool w0 = (t < 64);
  int lane = t & 63, w4 = t >> 6;
  for (int k = 0; k < 62; k++) {
    float beta = 0.f;
    if (w0) {
      float acol = S.A[t][k];
      float xs = (t >= k + 2) ? acol : 0.f;
      float sigma = wredsum(xs * xs);
      float x1 = __shfl(acol, k + 1, WF);
      float alpha = -copysignf(sqrtf(fmaf(x1, x1, sigma)), x1);
      float v1 = x1 - alpha;
      float vv = fmaf(v1, v1, sigma);
      beta = (vv > 1e-37f) ? 2.f / vv : 0.f;
      S.vbuf[t] = (t == k + 1) ? v1 : xs;
      if (t == 0) S.esh[k] = alpha;
    }
    __syncthreads();
    {
      // wave-uniform j -> skip terms with vbuf[j]==0 (j<=k)
      float s0 = 0.f, s1 = 0.f, s2 = 0.f, s3 = 0.f;
#pragma unroll
      for (int i2 = 0; i2 < 4; i2++) {
        int j = w4 + 16 * i2;
        if (j > k)      s0 = fmaf(S.A[lane][j], S.vbuf[j], s0);
        if (j + 4 > k)  s1 = fmaf(S.A[lane][j + 4], S.vbuf[j + 4], s1);
        if (j + 8 > k)  s2 = fmaf(S.A[lane][j + 8], S.vbuf[j + 8], s2);
        if (j + 12 > k) s3 = fmaf(S.A[lane][j + 12], S.vbuf[j + 12], s3);
      }
      S.wpart[w4][lane] = (s0 + s1) + (s2 + s3);
    }
    __syncthreads();
    if (w0) {
      float p = beta * (S.wpart[0][t] + S.wpart[1][t] + S.wpart[2][t] + S.wpart[3][t]);
      float dot = wredsum(S.vbuf[t] * p);
      float K = 0.5f * beta * dot;
      S.wbuf[t] = fmaf(-K, S.vbuf[t], p);
    }
    __syncthreads();
    {
      // wave-uniform i -> only update trailing rows
      float vj = S.vbuf[lane], wj = S.wbuf[lane];
#pragma unroll
      for (int i2 = 0; i2 < 16; i2++) {
        int i = w4 + 4 * i2;
        if (i > k) S.A[i][lane] -= S.vbuf[i] * wj + S.wbuf[i] * vj;
      }
    }
    __syncthreads();
  }
  if (t == 0) { S.esh[62] = S.A[63][62]; S.esh[63] = 0.f; }
  __syncthreads();
  float gmin = 0.f, gmax = 0.f;
  if (w0) {
    float dt = S.A[t][t];
    float ep = (t >= 1) ? S.esh[t - 1] : 0.f;
    float en = (t <= 62) ? S.esh[t] : 0.f;
    S.de[t] = make_float2(dt, ep * ep);
    float rad = fabsf(ep) + fabsf(en);
    gmin = wredmin(dt - rad);
    gmax = wredmax(dt + rad);
  }
  __syncthreads();
  float lam = 0.f;
  if (w0) {
    float range = gmax - gmin;
    float lo = gmin - 1e-3f * range - 1e-30f;
    float hi = gmax + 1e-3f * range + 1e-30f;
    for (int it = 0; it < 30; it++) {
      float mid = 0.5f * (lo + hi);
      float q = S.de[0].x - mid;
      int cnt = (q < 0.f) ? 1 : 0;
      for (int i = 1; i < 64; i++) {
        float2 dc = S.de[i];
        float qq = (dc.x - mid) - dc.y * fastrcp(q);
        q = (fabsf(qq) < 1e-30f) ? -1e-30f : qq;
        cnt += (q < 0.f) ? 1 : 0;
      }
      if (cnt > t) hi = mid; else lo = mid;
    }
    lam = 0.5f * (lo + hi);
  }
  float svv = w0 ? sqrtf(fmaxf(lam, 0.f)) : 0.f;
  return wredsum(svv);
}

// ---------------- one layer's rank pipeline (2 solves) ----------------
__device__ void rank_block(RankS& S, const float* __restrict__ Gl,
                           const float* __restrict__ rowslot_l,
                           const int* __restrict__ jstar_l,
                           float* __restrict__ rankOut_l, int t) {
  for (int idx = t; idx < 4096; idx += 256) S.A[idx >> 6][idx & 63] = Gl[idx];
  __syncthreads();
  float nuc1 = tridiag_sumsqrt(S, t);
  if (t == 0) S.shn = nuc1;
  __syncthreads();
  float s = 1.f / S.shn;
  int js = jstar_l[0];
  if (t < 64) {
    float rv = rowslot_l[t];
    float rn2 = wredsum(rv * rv);
    float sign = (rowslot_l[js] < 0.f) ? -1.f : 1.f;
    S.m0[t] = sign * rv * rsqrtf(rn2);
    S.u[t] = s * Gl[t * 64 + js] * rsqrtf(Gl[js * 64 + js]);
  }
  __syncthreads();
  float s2 = s * s;
  for (int idx = t; idx < 4096; idx += 256) {
    int i = idx >> 6, j = idx & 63;
    S.A[i][j] = s2 * Gl[idx] - S.u[i] * S.m0[j] - S.m0[i] * S.u[j] + S.m0[i] * S.m0[j];
  }
  __syncthreads();
  float nuc2 = tridiag_sumsqrt(S, t);
  if (t == 0) rankOut_l[0] = nuc2;
}

// ---------------- fused pass: [gram riders][rank rider][conv+energy blocks] ----------
// blockIdx < NG: gram of the INPUT Hb (prev layer stats). [NG, NG+NR): rank rider.
// rest: conv+energy, no barriers in main loop.
template <int LAST>
__global__ __launch_bounds__(256, 8) void k_convpass(
    const unsigned short* __restrict__ Hb, const float4* __restrict__ P,
    const float* __restrict__ nsq, const float* __restrict__ degsum,
    const float4* __restrict__ cn4, const int* __restrict__ start,
    const int* __restrict__ csr, const float* __restrict__ W,
    const float* __restrict__ bias, float* __restrict__ Tfp,
    unsigned short* __restrict__ Tb, float4* __restrict__ Pn,
    float* __restrict__ nsqN, float* __restrict__ scal5,
    int n, int NG, int NR, int nbC,
    float* __restrict__ Gg, float* __restrict__ colsumG,
    float* __restrict__ bmv, int* __restrict__ bmi,
    const float* __restrict__ Gr, const float* __restrict__ rowslotR,
    const int* __restrict__ jstarR, float* __restrict__ rankOutR) {
  __shared__ SmemU sm;
  int t = threadIdx.x, w = t >> 6, lane = t & 63, g = lane >> 4, l16 = lane & 15;
  if ((int)blockIdx.x < NG) {
    gram_block(sm.g, Hb, n, blockIdx.x, NG, Gg, colsumG, bmv, bmi, t);
    return;
  }
  if ((int)blockIdx.x < NG + NR) {
    rank_block(sm.r, Gr, rowslotR, jstarR, rankOutR, t);
    return;
  }
  for (int i = t; i < 4096; i += 256) sm.c.Wl[i] = W[i];
  __syncthreads();
  float a0 = 0.f, a1 = 0.f, a2 = 0.f, a3 = 0.f, a4 = 0.f;
  float bc = bias[lane];
  int wid = (blockIdx.x - NG - NR) * 4 + w, nw = nbC * 4;
  for (int d = wid; d < n; d += nw) {
    int k0 = start[d], k1 = start[d + 1];
    ushort4 hdb = *(const ushort4*)(Hb + (size_t)d * 64 + 4 * l16);
    float4 hd = make_float4(bf2f(hdb.x), bf2f(hdb.y), bf2f(hdb.z), bf2f(hdb.w));
    float4 pd = P[d];
    float nqd = nsq[d];
    float dsum = degsum[d];
    float4 agg0 = {0.f, 0.f, 0.f, 0.f};
    float4 agg1 = {0.f, 0.f, 0.f, 0.f};
    float4 aggC = {0.f, 0.f, 0.f, 0.f};
    float su = 0.f, sv = 0.f;
    gather4B<1>(Hb, P, csr, k0, k1, g, l16, agg0, agg1, aggC, su, sv);
    float td0 = agg0.x * hd.x + agg0.y * hd.y + agg0.z * hd.z + agg0.w * hd.w;
    float td1 = agg1.x * hd.x + agg1.y * hd.y + agg1.z * hd.z + agg1.w * hd.w;
    float4 r4 = wredsum4(make_float4(td0, td1, su, sv));
    a0 += dsum * nqd;
    a1 += r4.x;
    a2 += pd.z * (r4.z * 0.0625f) + pd.w * (r4.w * 0.0625f);
    a3 += pd.y * r4.y;
    a4 += nqd;
    // conv finish
    aggC.x += __shfl_xor(aggC.x, 16); aggC.y += __shfl_xor(aggC.y, 16);
    aggC.z += __shfl_xor(aggC.z, 16); aggC.w += __shfl_xor(aggC.w, 16);
    aggC.x += __shfl_xor(aggC.x, 32); aggC.y += __shfl_xor(aggC.y, 32);
    aggC.z += __shfl_xor(aggC.z, 32); aggC.w += __shfl_xor(aggC.w, 32);
    float mv = 0.f;
#pragma unroll
    for (int kq = 0; kq < 16; kq++) {
      float ax = __shfl(aggC.x, kq, 16);
      float ay = __shfl(aggC.y, kq, 16);
      float az = __shfl(aggC.z, kq, 16);
      float aw = __shfl(aggC.w, kq, 16);
      mv += ax * sm.c.Wl[(4 * kq + 0) * 64 + lane];
      mv += ay * sm.c.Wl[(4 * kq + 1) * 64 + lane];
      mv += az * sm.c.Wl[(4 * kq + 2) * 64 + lane];
      mv += aw * sm.c.Wl[(4 * kq + 3) * 64 + lane];
    }
    float tv = fmaxf(fmaf(pd.x, mv, bc), 0.f);
    if (LAST) Tfp[(size_t)d * 64 + lane] = tv;
    Tb[(size_t)d * 64 + lane] = f2bf(tv);
    float r = wredsum(tv * tv);
    if (lane == 0) {
      nsqN[d] = r;
      float4 c4 = cn4[d];
      Pn[d] = make_float4(c4.x, c4.y, c4.z, r * c4.w);
    }
  }
  if (lane == 0) {
    sm.c.red[w][0] = a0; sm.c.red[w][1] = a1; sm.c.red[w][2] = a2;
    sm.c.red[w][3] = a3; sm.c.red[w][4] = a4;
  }
  __syncthreads();
  if (t == 0) {
#pragma unroll
    for (int j = 0; j < 5; j++)
      atomAddF(&scal5[j], sm.c.red[0][j] + sm.c.red[1][j] + sm.c.red[2][j] + sm.c.red[3][j]);
  }
}

// ---------------- finalize argmaxes (one wave) ----------------
__global__ __launch_bounds__(64) void k_finalize(const unsigned short* Tb, const float* bmv,
                                                 const int* bmi, int nblocks,
                                                 const float* colsum, float* rowslot,
                                                 int* jstar, int n) {
  int t = threadIdx.x;
  float bv = -1.f;
  int bix = 0x7fffffff;
  for (int b = t; b < nblocks; b += 64) {
    float v = bmv[b]; int ix = bmi[b];
    if (v > bv || (v == bv && ix < bix)) { bv = v; bix = ix; }
  }
#pragma unroll
  for (int m = 32; m; m >>= 1) {
    float ov = __shfl_xor(bv, m); int oi = __shfl_xor(bix, m);
    if (ov > bv || (ov == bv && oi < bix)) { bv = ov; bix = oi; }
  }
  float cv = colsum[t];
  int cj = t;
#pragma unroll
  for (int m = 32; m; m >>= 1) {
    float ov = __shfl_xor(cv, m); int oj = __shfl_xor(cj, m);
    if (ov > cv || (ov == cv && oj < cj)) { cv = ov; cj = oj; }
  }
  if (t == 0) jstar[0] = cj;
  rowslot[t] = bf2f(Tb[(size_t)bix * 64 + t]);
}

// ---------------- final: [gram3 riders][rank2 rider][energy(h3) blocks] --------------
__global__ __launch_bounds__(256) void k_final(
    const unsigned short* __restrict__ Hb, const float4* __restrict__ P,
    const float* __restrict__ nsq, const float* __restrict__ degsum,
    const int* __restrict__ start, const int* __restrict__ csr,
    float* __restrict__ scal5, int n, int NG, int nbE,
    float* __restrict__ Gg, float* __restrict__ colsumG,
    float* __restrict__ bmv, int* __restrict__ bmi,
    const float* __restrict__ Gr, const float* __restrict__ rowslotR,
    const int* __restrict__ jstarR, float* __restrict__ rankOutR) {
  __shared__ SmemU sm;
  int t = threadIdx.x, w = t >> 6, lane = t & 63, g = lane >> 4, l16 = lane & 15;
  if ((int)blockIdx.x < NG) {
    gram_block(sm.g, Hb, n, blockIdx.x, NG, Gg, colsumG, bmv, bmi, t);
    return;
  }
  if ((int)blockIdx.x == NG) {
    rank_block(sm.r, Gr, rowslotR, jstarR, rankOutR, t);
    return;
  }
  float a0 = 0.f, a1 = 0.f, a2 = 0.f, a3 = 0.f, a4 = 0.f;
  int wid = (blockIdx.x - NG - 1) * 4 + w, nw = nbE * 4;
  for (int d = wid; d < n; d += nw) {
    int k0 = start[d], k1 = start[d + 1];
    ushort4 hdb = *(const ushort4*)(Hb + (size_t)d * 64 + 4 * l16);
    float4 hd = make_float4(bf2f(hdb.x), bf2f(hdb.y), bf2f(hdb.z), bf2f(hdb.w));
    float4 pd = P[d];
    float nqd = nsq[d];
    float dsum = degsum[d];
    float4 agg0 = {0.f, 0.f, 0.f, 0.f};
    float4 agg1 = {0.f, 0.f, 0.f, 0.f};
    float4 aggC = {0.f, 0.f, 0.f, 0.f};
    float su = 0.f, sv = 0.f;
    gather4B<0>(Hb, P, csr, k0, k1, g, l16, agg0, agg1, aggC, su, sv);
    float td0 = agg0.x * hd.x + agg0.y * hd.y + agg0.z * hd.z + agg0.w * hd.w;
    float td1 = agg1.x * hd.x + agg1.y * hd.y + agg1.z * hd.z + agg1.w * hd.w;
    float4 r4 = wredsum4(make_float4(td0, td1, su, sv));
    a0 += dsum * nqd;
    a1 += r4.x;
    a2 += pd.z * (r4.z * 0.0625f) + pd.w * (r4.w * 0.0625f);
    a3 += pd.y * r4.y;
    a4 += nqd;
  }
  if (lane == 0) {
    sm.c.red[w][0] = a0; sm.c.red[w][1] = a1; sm.c.red[w][2] = a2;
    sm.c.red[w][3] = a3; sm.c.red[w][4] = a4;
  }
  __syncthreads();
  if (t == 0) {
#pragma unroll
    for (int j = 0; j < 5; j++)
      atomAddF(&scal5[j], sm.c.red[0][j] + sm.c.red[1][j] + sm.c.red[2][j] + sm.c.red[3][j]);
  }
}

// ---------------- rank layer 3 (serial tail) ----------------
__global__ __launch_bounds__(256) void k_rank3(const float* Gl, const float* rowslot_l,
                                               const int* jstar_l, float* out) {
  __shared__ RankS S;
  rank_block(S, Gl, rowslot_l, jstar_l, out, threadIdx.x);
}

// ---------------- epilogue ----------------
__global__ __launch_bounds__(64) void k_epi(const float* scal, float* outsc) {
  if (threadIdx.x == 0) {
    for (int st = 0; st < 4; st++) {
      const float* a = scal + 5 * st;
      float inv = 1.f / a[4];
      float rw = 0.5f * (a[0] - 2.f * a[1]) * inv;
      float sym = 0.5f * (a[2] - 2.f * a[3]) * inv;
      if (st == 0) outsc[0] = sym;
      else { outsc[st] = rw; outsc[3 + st] = sym; }
    }
    for (int l = 0; l < 3; l++) outsc[7 + l] = scal[20 + l];
  }
}

extern "C" void kernel_launch(void* const* d_in, const int* in_sizes, int n_in,
                              void* d_out, int out_size, void* d_ws, size_t ws_size,
                              hipStream_t stream) {
  const float* x      = (const float*)d_in[0];
  const int*   ei     = (const int*)d_in[1];
  const float* enc_w  = (const float*)d_in[2];
  const float* enc_b  = (const float*)d_in[3];
  const float* conv_w = (const float*)d_in[4];
  const float* conv_b = (const float*)d_in[5];
  const int n = in_sizes[0] / 128;
  const int e = in_sizes[1] / 2;
  const int* src = ei;
  const int* dst = ei + e;
  float* OUT = (float*)d_out;
  float* outsc = OUT + (size_t)n * 64;

  char* p = (char*)d_ws;
  auto alloc = [&](size_t bytes) -> char* {
    char* r = p;
    p += (bytes + 255) & ~size_t(255);
    return r;
  };
  unsigned short* Xb     = (unsigned short*)alloc((size_t)n * 64 * 2);  // bf16 h0/h2
  unsigned short* Ybb    = (unsigned short*)alloc((size_t)n * 64 * 2);  // bf16 h1
  unsigned short* OUTb   = (unsigned short*)alloc((size_t)n * 64 * 2);  // bf16 h3
  int*            csr    = (int*)alloc((size_t)(e + n) * 4);
  int*            degs   = (int*)alloc((size_t)n * 4);
  int*            degd   = (int*)alloc((size_t)n * 4);
  float4*         cn4    = (float4*)alloc((size_t)n * 16);
  float*          degsum = (float*)alloc((size_t)n * 4);
  int*            start  = (int*)alloc((size_t)(n + 1) * 4);
  int*            cursor = (int*)alloc((size_t)n * 4);
  int*            bsum   = (int*)alloc(4096);
  float*          nsqA   = (float*)alloc((size_t)n * 4);
  float*          nsqB   = (float*)alloc((size_t)n * 4);
  float4*         Pa     = (float4*)alloc((size_t)n * 16);
  float4*         Pb     = (float4*)alloc((size_t)n * 16);
  float*          G      = (float*)alloc(3 * 4096 * 4);
  float*          colsum = (float*)alloc(3 * 64 * 4);
  float*          bmv    = (float*)alloc(2048 * 4);
  int*            bmi    = (int*)alloc(2048 * 4);
  float*          rowslot= (float*)alloc(3 * 64 * 4);
  float*          scal   = (float*)alloc(64 * 4);
  int*            ij     = (int*)alloc(64 * 4);

  int nb = (n + 255) / 256;
  const int NBL = 2048;
  const int NG = 256;

  k_init<<<nb, 256, 0, stream>>>(degs, degd, G, colsum, scal, n);
  k_deg<<<2048, 256, 0, stream>>>(src, dst, degs, degd, e);
  k_scan1<<<nb, 256, 0, stream>>>(degd, start, bsum, n);
  k_scan2<<<1, 512, 0, stream>>>(bsum, nb);
  k_scan3<<<nb, 256, 0, stream>>>(start, bsum, cursor, degs, degd, cn4, degsum, n, e + n);
  k_scatter<<<(e + n + 255) / 256, 256, 0, stream>>>(src, dst, cursor, csr, e, n);
  k_enc<<<NBL, 256, 0, stream>>>(x, enc_w, enc_b, cn4, Xb, nsqA, Pa, n);

  // pass 0: energy(h0) + conv0 -> h1   [no riders]
  k_convpass<0><<<NBL, 256, 0, stream>>>(Xb, Pa, nsqA, degsum, cn4, start, csr,
                                         conv_w, conv_b, nullptr, Ybb, Pb, nsqB,
                                         scal, n, 0, 0, NBL,
                                         nullptr, nullptr, nullptr, nullptr,
                                         nullptr, nullptr, nullptr, nullptr);

  // pass 1: energy(h1) + conv1 -> h2  || gram(h1) riders
  k_convpass<0><<<NBL + NG, 256, 0, stream>>>(Ybb, Pb, nsqB, degsum, cn4, start, csr,
                                              conv_w + 4096, conv_b + 64, nullptr, Xb, Pa, nsqA,
                                              scal + 5, n, NG, 0, NBL,
                                              G, colsum, bmv, bmi,
                                              nullptr, nullptr, nullptr, nullptr);
  k_finalize<<<1, 64, 0, stream>>>(Ybb, bmv, bmi, NG, colsum, rowslot, ij, n);

  // pass 2: energy(h2) + conv2 -> h3 (fp32+bf16)  || gram(h2) riders || rank1 rider
  k_convpass<1><<<NBL + NG + 1, 256, 0, stream>>>(Xb, Pa, nsqA, degsum, cn4, start, csr,
                                                  conv_w + 2 * 4096, conv_b + 128, OUT, OUTb,
                                                  Pb, nsqB, scal + 10, n, NG, 1, NBL,
                                                  G + 4096, colsum + 64, bmv, bmi,
                                                  G, rowslot, ij, scal + 20);
  k_finalize<<<1, 64, 0, stream>>>(Xb, bmv, bmi, NG, colsum + 64, rowslot + 64, ij + 1, n);

  // final: energy(h3) || gram(h3) riders || rank2 rider
  k_final<<<NBL + NG + 1, 256, 0, stream>>>(OUTb, Pb, nsqB, degsum, start, csr,
                                            scal + 15, n, NG, NBL,
                                            G + 2 * 4096, colsum + 128, bmv, bmi,
                                            G + 4096, rowslot + 64, ij + 1, scal + 21);
  k_finalize<<<1, 64, 0, stream>>>(OUTb, bmv, bmi, NG, colsum + 128, rowslot + 128, ij + 2, n);

  // rank layer 3 (serial tail)
  k_rank3<<<1, 256, 0, stream>>>(G + 2 * 4096, rowslot + 128, ij + 2, scal + 22);
  k_epi<<<1, 64, 0, stream>>>(scal, outsc);
}

// Round 10
// 1578.150 us; speedup vs baseline: 1.7903x; 1.7903x over previous
//
#include <hip/hip_runtime.h>

#define WF 64

__device__ inline float wredsum(float v) {
#pragma unroll
  for (int m = 32; m; m >>= 1) v += __shfl_xor(v, m, WF);
  return v;
}
__device__ inline float4 wredsum4(float4 v) {
#pragma unroll
  for (int m = 32; m; m >>= 1) {
    v.x += __shfl_xor(v.x, m, WF);
    v.y += __shfl_xor(v.y, m, WF);
    v.z += __shfl_xor(v.z, m, WF);
    v.w += __shfl_xor(v.w, m, WF);
  }
  return v;
}
__device__ inline float wredmin(float v) {
#pragma unroll
  for (int m = 32; m; m >>= 1) v = fminf(v, __shfl_xor(v, m, WF));
  return v;
}
__device__ inline float wredmax(float v) {
#pragma unroll
  for (int m = 32; m; m >>= 1) v = fmaxf(v, __shfl_xor(v, m, WF));
  return v;
}

__device__ inline float fastrcp(float x) {
  float r;
  asm("v_rcp_f32 %0, %1" : "=v"(r) : "v"(x));
  return r;
}

__device__ inline void atomAddF(float* p, float v) { unsafeAtomicAdd(p, v); }

// ---------------- shared-memory union ----------------
struct ConvS {
  float Wl[4096];
  float rowbuf[4][64];
  float red[4][5];
  float colred[4][64];
  float mvs[4];
  int mis[4];
};
struct GramS {
  float rowbuf[4][64];
  float colred[4][64];
  float mvs[4];
  int mis[4];
};
struct RankS {
  float A[64][65];
  float vbuf[64], wbuf[64], esh[64];
  float wpart[4][64];
  float2 de[64];
  float u[64], m0[64];
  float shn;
};
union SmemU {
  ConvS c;
  GramS g;
  RankS r;
};

// ---------------- init ----------------
__global__ __launch_bounds__(256) void k_init(int* degs, int* degd, float* G,
                                              float* colsum, float* scal, int n) {
  int i = blockIdx.x * 256 + threadIdx.x;
  if (i < n) { degs[i] = 1; degd[i] = 1; }
  if (i < 3 * 4096) G[i] = 0.f;
  if (i < 3 * 64) colsum[i] = 0.f;
  if (i < 64) scal[i] = 0.f;
}

// ---------------- degree histograms ----------------
__global__ __launch_bounds__(256) void k_deg(const int* src, const int* dst,
                                             int* degs, int* degd, int e) {
  int i = blockIdx.x * 256 + threadIdx.x;
  int stride = gridDim.x * 256;
  for (; i < e; i += stride) {
    atomicAdd(&degs[src[i]], 1);
    atomicAdd(&degd[dst[i]], 1);
  }
}

// ---------------- scan ----------------
__global__ __launch_bounds__(256) void k_scan1(const int* degd, int* start, int* bsum, int n) {
  __shared__ int sb[256];
  int t = threadIdx.x, i = blockIdx.x * 256 + t;
  int v = (i < n) ? degd[i] : 0;
  sb[t] = v;
  __syncthreads();
  for (int off = 1; off < 256; off <<= 1) {
    int add = (t >= off) ? sb[t - off] : 0;
    __syncthreads();
    sb[t] += add;
    __syncthreads();
  }
  if (i < n) start[i] = sb[t] - v;
  if (t == 255) bsum[blockIdx.x] = sb[255];
}

__global__ __launch_bounds__(512) void k_scan2(int* bsum, int nb) {
  __shared__ int sb[512];
  int t = threadIdx.x;
  int v = (t < nb) ? bsum[t] : 0;
  sb[t] = v;
  __syncthreads();
  for (int off = 1; off < 512; off <<= 1) {
    int add = (t >= off) ? sb[t - off] : 0;
    __syncthreads();
    sb[t] += add;
    __syncthreads();
  }
  if (t < nb) bsum[t] = sb[t] - v;
}

// scan3 + per-node constants: cn4 = {dis, 1/degs, degs^-0.5, degs^-1.5}
__global__ __launch_bounds__(256) void k_scan3(int* start, const int* bsum, int* cursor,
                                               const int* degs, const int* degd,
                                               float4* cn4, float* degsum, int n, int total) {
  int i = blockIdx.x * 256 + threadIdx.x;
  if (i < n) {
    int v = start[i] + bsum[i >> 8];
    start[i] = v;
    cursor[i] = v;
    float fs = (float)degs[i], fd = (float)degd[i];
    float rs_ = rsqrtf(fs);
    cn4[i] = make_float4(rsqrtf(fd), 1.f / fs, rs_, rs_ * rs_ * rs_);
    degsum[i] = fs + fd;
  }
  if (i == 0) start[n] = total;
}

// ---------------- counting-sort edges by dst ----------------
__global__ __launch_bounds__(256) void k_scatter(const int* src, const int* dst, int* cursor,
                                                 int* csr, int e, int n) {
  int i = blockIdx.x * 256 + threadIdx.x;
  int tot = e + n;
  if (i >= tot) return;
  int s, d;
  if (i < e) { s = src[i]; d = dst[i]; } else { s = i - e; d = i - e; }
  int pos = atomicAdd(&cursor[d], 1);
  csr[pos] = s;
}

// ---------------- encoder: X = x @ enc_w + b ; nsq, P0 ----------------
__global__ __launch_bounds__(256) void k_enc(const float* __restrict__ x,
                                             const float* __restrict__ W,
                                             const float* __restrict__ b,
                                             const float4* __restrict__ cn4,
                                             float* __restrict__ X,
                                             float* __restrict__ nsq,
                                             float4* __restrict__ P, int n) {
  __shared__ float Wl[128 * 64];
  for (int idx = threadIdx.x; idx < 128 * 64; idx += 256) Wl[idx] = W[idx];
  __syncthreads();
  int w = threadIdx.x >> 6, c = threadIdx.x & 63;
  float bc = b[c];
  for (int node = blockIdx.x * 4 + w; node < n; node += gridDim.x * 4) {
    const float4* xr4 = (const float4*)(x + (size_t)node * 128);
    float acc = bc;
#pragma unroll
    for (int k4 = 0; k4 < 32; k4++) {
      float4 xv = xr4[k4];
      acc += xv.x * Wl[(k4 * 4 + 0) * 64 + c];
      acc += xv.y * Wl[(k4 * 4 + 1) * 64 + c];
      acc += xv.z * Wl[(k4 * 4 + 2) * 64 + c];
      acc += xv.w * Wl[(k4 * 4 + 3) * 64 + c];
    }
    X[(size_t)node * 64 + c] = acc;
    float r = wredsum(acc * acc);
    if (c == 0) {
      nsq[node] = r;
      float4 c4 = cn4[node];
      P[node] = make_float4(c4.x, c4.y, c4.z, r * c4.w);
    }
  }
}

// ---------------- 4-deep unrolled fp32 gather core (per 16-lane group) -------------
// P = {dis, 1/deg, rs, nsq*deg^-1.5}. Per-edge p = h_s.h_d (slice dot);
// dot1 += p ; dot2 += p/deg_s ; aggC += dis_s*h_s (AGGC) ; su/sv per-edge scalars.
template <int AGGC>
__device__ inline void gather4F(const float* __restrict__ H, const float4* __restrict__ P,
                                const int* __restrict__ csr, int k0, int k1, int g, int l16,
                                const float4& hd, float& dot1, float& dot2,
                                float4& aggC, float& su, float& sv) {
  int kk = k0 + g;
  int last = k1 - 1;
  int s0 = csr[min(kk, last)];
  int s1 = csr[min(kk + 4, last)];
  int s2 = csr[min(kk + 8, last)];
  int s3 = csr[min(kk + 12, last)];
  while (kk < k1) {
    int kn = kk + 16;
    float4 h0 = *(const float4*)(H + (size_t)s0 * 64 + 4 * l16);
    float4 h1 = *(const float4*)(H + (size_t)s1 * 64 + 4 * l16);
    float4 h2 = *(const float4*)(H + (size_t)s2 * 64 + 4 * l16);
    float4 h3 = *(const float4*)(H + (size_t)s3 * 64 + 4 * l16);
    float4 Q0 = P[s0], Q1 = P[s1], Q2 = P[s2], Q3 = P[s3];
    s0 = csr[min(kn, last)];
    s1 = csr[min(kn + 4, last)];
    s2 = csr[min(kn + 8, last)];
    s3 = csr[min(kn + 12, last)];
    float m1 = (kk + 4 < k1) ? 1.f : 0.f;
    float m2 = (kk + 8 < k1) ? 1.f : 0.f;
    float m3 = (kk + 12 < k1) ? 1.f : 0.f;
    // slot 0 (always valid)
    {
      float p = h0.x * hd.x + h0.y * hd.y + h0.z * hd.z + h0.w * hd.w;
      dot1 += p;
      dot2 = fmaf(p, Q0.y, dot2);
      su += Q0.w; sv += Q0.z;
      if (AGGC) {
        aggC.x = fmaf(h0.x, Q0.x, aggC.x); aggC.y = fmaf(h0.y, Q0.x, aggC.y);
        aggC.z = fmaf(h0.z, Q0.x, aggC.z); aggC.w = fmaf(h0.w, Q0.x, aggC.w);
      }
    }
    // slots 1..3 masked
    {
      float p = h1.x * hd.x + h1.y * hd.y + h1.z * hd.z + h1.w * hd.w;
      dot1 = fmaf(p, m1, dot1);
      dot2 = fmaf(p, Q1.y * m1, dot2);
      su = fmaf(Q1.w, m1, su); sv = fmaf(Q1.z, m1, sv);
      if (AGGC) {
        float xq = Q1.x * m1;
        aggC.x = fmaf(h1.x, xq, aggC.x); aggC.y = fmaf(h1.y, xq, aggC.y);
        aggC.z = fmaf(h1.z, xq, aggC.z); aggC.w = fmaf(h1.w, xq, aggC.w);
      }
    }
    {
      float p = h2.x * hd.x + h2.y * hd.y + h2.z * hd.z + h2.w * hd.w;
      dot1 = fmaf(p, m2, dot1);
      dot2 = fmaf(p, Q2.y * m2, dot2);
      su = fmaf(Q2.w, m2, su); sv = fmaf(Q2.z, m2, sv);
      if (AGGC) {
        float xq = Q2.x * m2;
        aggC.x = fmaf(h2.x, xq, aggC.x); aggC.y = fmaf(h2.y, xq, aggC.y);
        aggC.z = fmaf(h2.z, xq, aggC.z); aggC.w = fmaf(h2.w, xq, aggC.w);
      }
    }
    {
      float p = h3.x * hd.x + h3.y * hd.y + h3.z * hd.z + h3.w * hd.w;
      dot1 = fmaf(p, m3, dot1);
      dot2 = fmaf(p, Q3.y * m3, dot2);
      su = fmaf(Q3.w, m3, su); sv = fmaf(Q3.z, m3, sv);
      if (AGGC) {
        float xq = Q3.x * m3;
        aggC.x = fmaf(h3.x, xq, aggC.x); aggC.y = fmaf(h3.y, xq, aggC.y);
        aggC.z = fmaf(h3.z, xq, aggC.z); aggC.w = fmaf(h3.w, xq, aggC.w);
      }
    }
    kk = kn;
  }
}

// ---------------- streaming Gram/colsum/argmax of fp32 matrix (rider) --------------
__device__ void gram_block(GramS& S, const float* __restrict__ H, int n,
                           int gid, int NG, float* __restrict__ G,
                           float* __restrict__ colsum, float* __restrict__ bmv,
                           int* __restrict__ bmi, int t) {
  int w = t >> 6, lane = t & 63;
  int chunk = (n + NG - 1) / NG;
  int r0 = gid * chunk;
  int r1 = min(n, r0 + chunk);
  float Greg[16];
#pragma unroll
  for (int k = 0; k < 16; k++) Greg[k] = 0.f;
  float cacc = 0.f, best = -1.f;
  int bi = 0;
  int iters = (r1 - r0 + 3) >> 2;
  for (int it = 0; it < iters; it++) {
    int row = r0 + it * 4 + w;
    bool valid = row < r1;
    float v = valid ? H[(size_t)row * 64 + lane] : 0.f;
    float a = fabsf(v);
    cacc += a;
    float rsum = wredsum(a);
    if (valid && rsum > best) { best = rsum; bi = row; }
    S.rowbuf[w][lane] = v;
    __syncthreads();
#pragma unroll
    for (int rr = 0; rr < 4; rr++) {
      float hj = S.rowbuf[rr][lane];
#pragma unroll
      for (int k = 0; k < 16; k++) Greg[k] = fmaf(S.rowbuf[rr][w + 4 * k], hj, Greg[k]);
    }
    __syncthreads();
  }
#pragma unroll
  for (int k = 0; k < 16; k++) atomAddF(&G[(w + 4 * k) * 64 + lane], Greg[k]);
  S.colred[w][lane] = cacc;
  if (lane == 0) { S.mvs[w] = best; S.mis[w] = bi; }
  __syncthreads();
  if (t < 64) {
    float cs = S.colred[0][t] + S.colred[1][t] + S.colred[2][t] + S.colred[3][t];
    atomAddF(&colsum[t], cs);
  }
  if (t == 0) {
    float bv = S.mvs[0]; int bix = S.mis[0];
    for (int q = 1; q < 4; q++)
      if (S.mvs[q] > bv || (S.mvs[q] == bv && S.mis[q] < bix)) { bv = S.mvs[q]; bix = S.mis[q]; }
    bmv[gid] = bv;
    bmi[gid] = bix;
  }
}

// ---------------- Householder tridiag (trailing-only) + Sturm bisection --------------
__device__ float tridiag_sumsqrt(RankS& S, int t) {
  bool w0 = (t < 64);
  int lane = t & 63, w4 = t >> 6;
  for (int k = 0; k < 62; k++) {
    float beta = 0.f;
    if (w0) {
      float acol = S.A[t][k];
      float xs = (t >= k + 2) ? acol : 0.f;
      float sigma = wredsum(xs * xs);
      float x1 = __shfl(acol, k + 1, WF);
      float alpha = -copysignf(sqrtf(fmaf(x1, x1, sigma)), x1);
      float v1 = x1 - alpha;
      float vv = fmaf(v1, v1, sigma);
      beta = (vv > 1e-37f) ? 2.f / vv : 0.f;
      S.vbuf[t] = (t == k + 1) ? v1 : xs;
      if (t == 0) S.esh[k] = alpha;
    }
    __syncthreads();
    {
      float s0 = 0.f, s1 = 0.f, s2 = 0.f, s3 = 0.f;
#pragma unroll
      for (int i2 = 0; i2 < 4; i2++) {
        int j = w4 + 16 * i2;
        if (j > k)      s0 = fmaf(S.A[lane][j], S.vbuf[j], s0);
        if (j + 4 > k)  s1 = fmaf(S.A[lane][j + 4], S.vbuf[j + 4], s1);
        if (j + 8 > k)  s2 = fmaf(S.A[lane][j + 8], S.vbuf[j + 8], s2);
        if (j + 12 > k) s3 = fmaf(S.A[lane][j + 12], S.vbuf[j + 12], s3);
      }
      S.wpart[w4][lane] = (s0 + s1) + (s2 + s3);
    }
    __syncthreads();
    if (w0) {
      float p = beta * (S.wpart[0][t] + S.wpart[1][t] + S.wpart[2][t] + S.wpart[3][t]);
      float dot = wredsum(S.vbuf[t] * p);
      float K = 0.5f * beta * dot;
      S.wbuf[t] = fmaf(-K, S.vbuf[t], p);
    }
    __syncthreads();
    {
      float vj = S.vbuf[lane], wj = S.wbuf[lane];
#pragma unroll
      for (int i2 = 0; i2 < 16; i2++) {
        int i = w4 + 4 * i2;
        if (i > k) S.A[i][lane] -= S.vbuf[i] * wj + S.wbuf[i] * vj;
      }
    }
    __syncthreads();
  }
  if (t == 0) { S.esh[62] = S.A[63][62]; S.esh[63] = 0.f; }
  __syncthreads();
  float gmin = 0.f, gmax = 0.f;
  if (w0) {
    float dt = S.A[t][t];
    float ep = (t >= 1) ? S.esh[t - 1] : 0.f;
    float en = (t <= 62) ? S.esh[t] : 0.f;
    S.de[t] = make_float2(dt, ep * ep);
    float rad = fabsf(ep) + fabsf(en);
    gmin = wredmin(dt - rad);
    gmax = wredmax(dt + rad);
  }
  __syncthreads();
  float lam = 0.f;
  if (w0) {
    float range = gmax - gmin;
    float lo = gmin - 1e-3f * range - 1e-30f;
    float hi = gmax + 1e-3f * range + 1e-30f;
    for (int it = 0; it < 30; it++) {
      float mid = 0.5f * (lo + hi);
      float q = S.de[0].x - mid;
      int cnt = (q < 0.f) ? 1 : 0;
      for (int i = 1; i < 64; i++) {
        float2 dc = S.de[i];
        float qq = (dc.x - mid) - dc.y * fastrcp(q);
        q = (fabsf(qq) < 1e-30f) ? -1e-30f : qq;
        cnt += (q < 0.f) ? 1 : 0;
      }
      if (cnt > t) hi = mid; else lo = mid;
    }
    lam = 0.5f * (lo + hi);
  }
  float svv = w0 ? sqrtf(fmaxf(lam, 0.f)) : 0.f;
  return wredsum(svv);
}

// ---------------- one layer's rank pipeline (2 solves) ----------------
__device__ void rank_block(RankS& S, const float* __restrict__ Gl,
                           const float* __restrict__ rowslot_l,
                           const int* __restrict__ jstar_l,
                           float* __restrict__ rankOut_l, int t) {
  for (int idx = t; idx < 4096; idx += 256) S.A[idx >> 6][idx & 63] = Gl[idx];
  __syncthreads();
  float nuc1 = tridiag_sumsqrt(S, t);
  if (t == 0) S.shn = nuc1;
  __syncthreads();
  float s = 1.f / S.shn;
  int js = jstar_l[0];
  if (t < 64) {
    float rv = rowslot_l[t];
    float rn2 = wredsum(rv * rv);
    float sign = (rowslot_l[js] < 0.f) ? -1.f : 1.f;
    S.m0[t] = sign * rv * rsqrtf(rn2);
    S.u[t] = s * Gl[t * 64 + js] * rsqrtf(Gl[js * 64 + js]);
  }
  __syncthreads();
  float s2 = s * s;
  for (int idx = t; idx < 4096; idx += 256) {
    int i = idx >> 6, j = idx & 63;
    S.A[i][j] = s2 * Gl[idx] - S.u[i] * S.m0[j] - S.m0[i] * S.u[j] + S.m0[i] * S.m0[j];
  }
  __syncthreads();
  float nuc2 = tridiag_sumsqrt(S, t);
  if (t == 0) rankOut_l[0] = nuc2;
}

// ---------------- fused pass: [gram riders][rank rider][conv+energy] ----------------
// GRAMLOOP=1: lockstep loop + in-loop gram of the NEW h (for the last layer).
template <int GRAMLOOP>
__global__ __launch_bounds__(256) void k_convpass(
    const float* __restrict__ H, const float4* __restrict__ P,
    const float* __restrict__ nsq, const float* __restrict__ degsum,
    const float4* __restrict__ cn4, const int* __restrict__ start,
    const int* __restrict__ csr, const float* __restrict__ W,
    const float* __restrict__ bias, float* __restrict__ T,
    float4* __restrict__ Pn, float* __restrict__ nsqN, float* __restrict__ scal5,
    int n, int NG, int NR, int nbC,
    float* __restrict__ Gg, float* __restrict__ colsumG,
    float* __restrict__ bmvG, int* __restrict__ bmiG,
    float* __restrict__ Gl, float* __restrict__ colsumL,
    float* __restrict__ bmvL, int* __restrict__ bmiL,
    const float* __restrict__ Gr, const float* __restrict__ rowslotR,
    const int* __restrict__ jstarR, float* __restrict__ rankOutR) {
  __shared__ SmemU sm;
  int t = threadIdx.x, w = t >> 6, lane = t & 63, g = lane >> 4, l16 = lane & 15;
  if ((int)blockIdx.x < NG) {
    gram_block(sm.g, H, n, blockIdx.x, NG, Gg, colsumG, bmvG, bmiG, t);
    return;
  }
  if ((int)blockIdx.x < NG + NR) {
    rank_block(sm.r, Gr, rowslotR, jstarR, rankOutR, t);
    return;
  }
  int bid = blockIdx.x - NG - NR;
  for (int i = t; i < 4096; i += 256) sm.c.Wl[i] = W[i];
  __syncthreads();
  float a0 = 0.f, a1 = 0.f, a2 = 0.f, a3 = 0.f, a4 = 0.f;
  float bc = bias[lane];
  int wid = bid * 4 + w, nw = nbC * 4;

  float Greg[16];
  float cacc = 0.f, best = -1.f;
  int bi = 0;
  if (GRAMLOOP) {
#pragma unroll
    for (int k = 0; k < 16; k++) Greg[k] = 0.f;
  }

  int iters = GRAMLOOP ? (n + nw - 1) / nw : 0;
  int nloop = GRAMLOOP ? iters : 0;
  // unified loop: GRAMLOOP uses lockstep fixed trip count; else free-run
  if (GRAMLOOP) {
    for (int it = 0; it < nloop; it++) {
      int d = wid + it * nw;
      bool valid = d < n;
      float tv = 0.f;
      if (valid) {
        int k0 = start[d], k1 = start[d + 1];
        float4 hd = *(const float4*)(H + (size_t)d * 64 + 4 * l16);
        float4 pd = P[d];
        float nqd = nsq[d];
        float dsum = degsum[d];
        float dot1 = 0.f, dot2 = 0.f, su = 0.f, sv = 0.f;
        float4 aggC = {0.f, 0.f, 0.f, 0.f};
        gather4F<1>(H, P, csr, k0, k1, g, l16, hd, dot1, dot2, aggC, su, sv);
        float4 r4 = wredsum4(make_float4(dot1, dot2, su, sv));
        a0 += dsum * nqd;
        a1 += r4.x;
        a2 += pd.z * (r4.z * 0.0625f) + pd.w * (r4.w * 0.0625f);
        a3 += pd.y * r4.y;
        a4 += nqd;
        aggC.x += __shfl_xor(aggC.x, 16); aggC.y += __shfl_xor(aggC.y, 16);
        aggC.z += __shfl_xor(aggC.z, 16); aggC.w += __shfl_xor(aggC.w, 16);
        aggC.x += __shfl_xor(aggC.x, 32); aggC.y += __shfl_xor(aggC.y, 32);
        aggC.z += __shfl_xor(aggC.z, 32); aggC.w += __shfl_xor(aggC.w, 32);
        float mv = 0.f;
#pragma unroll
        for (int kq = 0; kq < 16; kq++) {
          float ax = __shfl(aggC.x, kq, 16);
          float ay = __shfl(aggC.y, kq, 16);
          float az = __shfl(aggC.z, kq, 16);
          float aw = __shfl(aggC.w, kq, 16);
          mv += ax * sm.c.Wl[(4 * kq + 0) * 64 + lane];
          mv += ay * sm.c.Wl[(4 * kq + 1) * 64 + lane];
          mv += az * sm.c.Wl[(4 * kq + 2) * 64 + lane];
          mv += aw * sm.c.Wl[(4 * kq + 3) * 64 + lane];
        }
        tv = fmaxf(fmaf(pd.x, mv, bc), 0.f);
        T[(size_t)d * 64 + lane] = tv;
        float r = wredsum(tv * tv);
        float atv = fabsf(tv);
        cacc += atv;
        float rsum = wredsum(atv);
        if (rsum > best) { best = rsum; bi = d; }
        if (lane == 0) {
          nsqN[d] = r;
          float4 c4 = cn4[d];
          Pn[d] = make_float4(c4.x, c4.y, c4.z, r * c4.w);
        }
      }
      sm.c.rowbuf[w][lane] = tv;
      __syncthreads();
#pragma unroll
      for (int rr = 0; rr < 4; rr++) {
        float hj = sm.c.rowbuf[rr][lane];
#pragma unroll
        for (int k = 0; k < 16; k++) Greg[k] = fmaf(sm.c.rowbuf[rr][w + 4 * k], hj, Greg[k]);
      }
      __syncthreads();
    }
  } else {
    for (int d = wid; d < n; d += nw) {
      int k0 = start[d], k1 = start[d + 1];
      float4 hd = *(const float4*)(H + (size_t)d * 64 + 4 * l16);
      float4 pd = P[d];
      float nqd = nsq[d];
      float dsum = degsum[d];
      float dot1 = 0.f, dot2 = 0.f, su = 0.f, sv = 0.f;
      float4 aggC = {0.f, 0.f, 0.f, 0.f};
      gather4F<1>(H, P, csr, k0, k1, g, l16, hd, dot1, dot2, aggC, su, sv);
      float4 r4 = wredsum4(make_float4(dot1, dot2, su, sv));
      a0 += dsum * nqd;
      a1 += r4.x;
      a2 += pd.z * (r4.z * 0.0625f) + pd.w * (r4.w * 0.0625f);
      a3 += pd.y * r4.y;
      a4 += nqd;
      aggC.x += __shfl_xor(aggC.x, 16); aggC.y += __shfl_xor(aggC.y, 16);
      aggC.z += __shfl_xor(aggC.z, 16); aggC.w += __shfl_xor(aggC.w, 16);
      aggC.x += __shfl_xor(aggC.x, 32); aggC.y += __shfl_xor(aggC.y, 32);
      aggC.z += __shfl_xor(aggC.z, 32); aggC.w += __shfl_xor(aggC.w, 32);
      float mv = 0.f;
#pragma unroll
      for (int kq = 0; kq < 16; kq++) {
        float ax = __shfl(aggC.x, kq, 16);
        float ay = __shfl(aggC.y, kq, 16);
        float az = __shfl(aggC.z, kq, 16);
        float aw = __shfl(aggC.w, kq, 16);
        mv += ax * sm.c.Wl[(4 * kq + 0) * 64 + lane];
        mv += ay * sm.c.Wl[(4 * kq + 1) * 64 + lane];
        mv += az * sm.c.Wl[(4 * kq + 2) * 64 + lane];
        mv += aw * sm.c.Wl[(4 * kq + 3) * 64 + lane];
      }
      float tv = fmaxf(fmaf(pd.x, mv, bc), 0.f);
      T[(size_t)d * 64 + lane] = tv;
      float r = wredsum(tv * tv);
      if (lane == 0) {
        nsqN[d] = r;
        float4 c4 = cn4[d];
        Pn[d] = make_float4(c4.x, c4.y, c4.z, r * c4.w);
      }
    }
  }

  if (GRAMLOOP) {
#pragma unroll
    for (int k = 0; k < 16; k++) atomAddF(&Gl[(w + 4 * k) * 64 + lane], Greg[k]);
    sm.c.colred[w][lane] = cacc;
    if (lane == 0) { sm.c.mvs[w] = best; sm.c.mis[w] = bi; }
  }
  if (lane == 0) {
    sm.c.red[w][0] = a0; sm.c.red[w][1] = a1; sm.c.red[w][2] = a2;
    sm.c.red[w][3] = a3; sm.c.red[w][4] = a4;
  }
  __syncthreads();
  if (GRAMLOOP && t < 64) {
    float cs = sm.c.colred[0][t] + sm.c.colred[1][t] + sm.c.colred[2][t] + sm.c.colred[3][t];
    atomAddF(&colsumL[t], cs);
  }
  if (t == 0) {
#pragma unroll
    for (int j = 0; j < 5; j++)
      atomAddF(&scal5[j], sm.c.red[0][j] + sm.c.red[1][j] + sm.c.red[2][j] + sm.c.red[3][j]);
    if (GRAMLOOP) {
      float bv = sm.c.mvs[0]; int bix = sm.c.mis[0];
      for (int q = 1; q < 4; q++)
        if (sm.c.mvs[q] > bv || (sm.c.mvs[q] == bv && sm.c.mis[q] < bix)) {
          bv = sm.c.mvs[q]; bix = sm.c.mis[q];
        }
      bmvL[bid] = bv;
      bmiL[bid] = bix;
    }
  }
}

// ---------------- finalize argmaxes (one wave) ----------------
__global__ __launch_bounds__(64) void k_finalize(const float* T, const float* bmv,
                                                 const int* bmi, int nblocks,
                                                 const float* colsum, float* rowslot,
                                                 int* jstar, int n) {
  int t = threadIdx.x;
  float bv = -1.f;
  int bix = 0x7fffffff;
  for (int b = t; b < nblocks; b += 64) {
    float v = bmv[b]; int ix = bmi[b];
    if (v > bv || (v == bv && ix < bix)) { bv = v; bix = ix; }
  }
#pragma unroll
  for (int m = 32; m; m >>= 1) {
    float ov = __shfl_xor(bv, m); int oi = __shfl_xor(bix, m);
    if (ov > bv || (ov == bv && oi < bix)) { bv = ov; bix = oi; }
  }
  float cv = colsum[t];
  int cj = t;
#pragma unroll
  for (int m = 32; m; m >>= 1) {
    float ov = __shfl_xor(cv, m); int oj = __shfl_xor(cj, m);
    if (ov > cv || (ov == cv && oj < cj)) { cv = ov; cj = oj; }
  }
  if (t == 0) jstar[0] = cj;
  rowslot[t] = T[(size_t)bix * 64 + t];
}

// ---------------- final: [rank2,rank3 riders][energy(h3) blocks] ----------------
__global__ __launch_bounds__(256) void k_final(
    const float* __restrict__ H, const float4* __restrict__ P,
    const float* __restrict__ nsq, const float* __restrict__ degsum,
    const int* __restrict__ start, const int* __restrict__ csr,
    float* __restrict__ scal5, int n, int NR, int nbE,
    const float* __restrict__ Gr, const float* __restrict__ rowslotR,
    const int* __restrict__ jstarR, float* __restrict__ rankOutR) {
  __shared__ SmemU sm;
  int t = threadIdx.x, w = t >> 6, lane = t & 63, g = lane >> 4, l16 = lane & 15;
  if ((int)blockIdx.x < NR) {
    int rl = blockIdx.x;
    rank_block(sm.r, Gr + rl * 4096, rowslotR + rl * 64, jstarR + rl, rankOutR + rl, t);
    return;
  }
  float a0 = 0.f, a1 = 0.f, a2 = 0.f, a3 = 0.f, a4 = 0.f;
  int wid = (blockIdx.x - NR) * 4 + w, nw = nbE * 4;
  for (int d = wid; d < n; d += nw) {
    int k0 = start[d], k1 = start[d + 1];
    float4 hd = *(const float4*)(H + (size_t)d * 64 + 4 * l16);
    float4 pd = P[d];
    float nqd = nsq[d];
    float dsum = degsum[d];
    float dot1 = 0.f, dot2 = 0.f, su = 0.f, sv = 0.f;
    float4 aggC = {0.f, 0.f, 0.f, 0.f};
    gather4F<0>(H, P, csr, k0, k1, g, l16, hd, dot1, dot2, aggC, su, sv);
    float4 r4 = wredsum4(make_float4(dot1, dot2, su, sv));
    a0 += dsum * nqd;
    a1 += r4.x;
    a2 += pd.z * (r4.z * 0.0625f) + pd.w * (r4.w * 0.0625f);
    a3 += pd.y * r4.y;
    a4 += nqd;
  }
  if (lane == 0) {
    sm.c.red[w][0] = a0; sm.c.red[w][1] = a1; sm.c.red[w][2] = a2;
    sm.c.red[w][3] = a3; sm.c.red[w][4] = a4;
  }
  __syncthreads();
  if (t == 0) {
#pragma unroll
    for (int j = 0; j < 5; j++)
      atomAddF(&scal5[j], sm.c.red[0][j] + sm.c.red[1][j] + sm.c.red[2][j] + sm.c.red[3][j]);
  }
}

// ---------------- epilogue ----------------
__global__ __launch_bounds__(64) void k_epi(const float* scal, float* outsc) {
  if (threadIdx.x == 0) {
    for (int st = 0; st < 4; st++) {
      const float* a = scal + 5 * st;
      float inv = 1.f / a[4];
      float rw = 0.5f * (a[0] - 2.f * a[1]) * inv;
      float sym = 0.5f * (a[2] - 2.f * a[3]) * inv;
      if (st == 0) outsc[0] = sym;
      else { outsc[st] = rw; outsc[3 + st] = sym; }
    }
    for (int l = 0; l < 3; l++) outsc[7 + l] = scal[20 + l];
  }
}

extern "C" void kernel_launch(void* const* d_in, const int* in_sizes, int n_in,
                              void* d_out, int out_size, void* d_ws, size_t ws_size,
                              hipStream_t stream) {
  const float* x      = (const float*)d_in[0];
  const int*   ei     = (const int*)d_in[1];
  const float* enc_w  = (const float*)d_in[2];
  const float* enc_b  = (const float*)d_in[3];
  const float* conv_w = (const float*)d_in[4];
  const float* conv_b = (const float*)d_in[5];
  const int n = in_sizes[0] / 128;
  const int e = in_sizes[1] / 2;
  const int* src = ei;
  const int* dst = ei + e;
  float* OUT = (float*)d_out;
  float* outsc = OUT + (size_t)n * 64;

  char* p = (char*)d_ws;
  auto alloc = [&](size_t bytes) -> char* {
    char* r = p;
    p += (bytes + 255) & ~size_t(255);
    return r;
  };
  float*  X      = (float*)alloc((size_t)n * 64 * 4);   // h0 / h2
  float*  Yf     = (float*)alloc((size_t)n * 64 * 4);   // h1
  int*    csr    = (int*)alloc((size_t)(e + n) * 4);
  int*    degs   = (int*)alloc((size_t)n * 4);
  int*    degd   = (int*)alloc((size_t)n * 4);
  float4* cn4    = (float4*)alloc((size_t)n * 16);
  float*  degsum = (float*)alloc((size_t)n * 4);
  int*    start  = (int*)alloc((size_t)(n + 1) * 4);
  int*    cursor = (int*)alloc((size_t)n * 4);
  int*    bsum   = (int*)alloc(4096);
  float*  nsqA   = (float*)alloc((size_t)n * 4);
  float*  nsqB   = (float*)alloc((size_t)n * 4);
  float4* Pa     = (float4*)alloc((size_t)n * 16);
  float4* Pb     = (float4*)alloc((size_t)n * 16);
  float*  G      = (float*)alloc(3 * 4096 * 4);
  float*  colsum = (float*)alloc(3 * 64 * 4);
  float*  bmvA   = (float*)alloc(2048 * 4);
  int*    bmiA   = (int*)alloc(2048 * 4);
  float*  bmvB   = (float*)alloc(256 * 4);
  int*    bmiB   = (int*)alloc(256 * 4);
  float*  rowslot= (float*)alloc(3 * 64 * 4);
  float*  scal   = (float*)alloc(64 * 4);
  int*    ij     = (int*)alloc(64 * 4);

  int nb = (n + 255) / 256;
  const int NBL = 2048;
  const int NG = 256;

  k_init<<<nb, 256, 0, stream>>>(degs, degd, G, colsum, scal, n);
  k_deg<<<2048, 256, 0, stream>>>(src, dst, degs, degd, e);
  k_scan1<<<nb, 256, 0, stream>>>(degd, start, bsum, n);
  k_scan2<<<1, 512, 0, stream>>>(bsum, nb);
  k_scan3<<<nb, 256, 0, stream>>>(start, bsum, cursor, degs, degd, cn4, degsum, n, e + n);
  k_scatter<<<(e + n + 255) / 256, 256, 0, stream>>>(src, dst, cursor, csr, e, n);
  k_enc<<<NBL, 256, 0, stream>>>(x, enc_w, enc_b, cn4, X, nsqA, Pa, n);

  // pass 0: energy(h0) + conv0 -> h1 (Yf). lean, no riders.
  k_convpass<0><<<NBL, 256, 0, stream>>>(X, Pa, nsqA, degsum, cn4, start, csr,
                                         conv_w, conv_b, Yf, Pb, nsqB, scal,
                                         n, 0, 0, NBL,
                                         nullptr, nullptr, nullptr, nullptr,
                                         nullptr, nullptr, nullptr, nullptr,
                                         nullptr, nullptr, nullptr, nullptr);

  // pass 1: energy(h1) + conv1 -> h2 (X). riders: gram(h1) -> G0.
  k_convpass<0><<<NBL + NG, 256, 0, stream>>>(Yf, Pb, nsqB, degsum, cn4, start, csr,
                                              conv_w + 4096, conv_b + 64, X, Pa, nsqA,
                                              scal + 5, n, NG, 0, NBL,
                                              G, colsum, bmvB, bmiB,
                                              nullptr, nullptr, nullptr, nullptr,
                                              nullptr, nullptr, nullptr, nullptr);
  k_finalize<<<1, 64, 0, stream>>>(Yf, bmvB, bmiB, NG, colsum, rowslot, ij, n);

  // pass 2: energy(h2) + conv2 -> h3 (OUT), in-loop gram(h3) -> G2.
  //         riders: gram(h2) -> G1, rank1 (G0).
  k_convpass<1><<<NBL + NG + 1, 256, 0, stream>>>(X, Pa, nsqA, degsum, cn4, start, csr,
                                                  conv_w + 2 * 4096, conv_b + 128, OUT, Pb, nsqB,
                                                  scal + 10, n, NG, 1, NBL,
                                                  G + 4096, colsum + 64, bmvB, bmiB,
                                                  G + 2 * 4096, colsum + 128, bmvA, bmiA,
                                                  G, rowslot, ij, scal + 20);
  k_finalize<<<1, 64, 0, stream>>>(X, bmvB, bmiB, NG, colsum + 64, rowslot + 64, ij + 1, n);
  k_finalize<<<1, 64, 0, stream>>>(OUT, bmvA, bmiA, NBL, colsum + 128, rowslot + 128, ij + 2, n);

  // final: energy(h3) || rank2 (G1), rank3 (G2) riders.
  k_final<<<NBL + 2, 256, 0, stream>>>(OUT, Pb, nsqB, degsum, start, csr,
                                       scal + 15, n, 2, NBL,
                                       G + 4096, rowslot + 64, ij + 1, scal + 21);
  k_epi<<<1, 64, 0, stream>>>(scal, outsc);
}